// Round 7
// baseline (1145.904 us; speedup 1.0000x reference)
//
#include <hip/hip_runtime.h>

#define NN 50000
#define NE 800000
#define NBK 1563          // ceil(NN/32) blocks of 32 nodes
#define NCH 49            // ceil(NN/1024) scan chunks

typedef __attribute__((ext_vector_type(8))) short short8;
typedef __attribute__((ext_vector_type(4))) float f32x4;

// ---- bf16 helpers (RTNE) ----
__device__ inline float blo(unsigned u) { return __uint_as_float(u << 16); }
__device__ inline float bhi(unsigned u) { return __uint_as_float(u & 0xffff0000u); }
__device__ inline unsigned short f2b(float f) {
    unsigned u = __float_as_uint(f);
    u += 0x7fff + ((u >> 16) & 1);
    return (unsigned short)(u >> 16);
}
__device__ inline unsigned packrtne(float a, float b) {
    unsigned ua = __float_as_uint(a); ua += 0x7fff + ((ua >> 16) & 1);
    unsigned ub = __float_as_uint(b); ub += 0x7fff + ((ub >> 16) & 1);
    return (ua >> 16) | (ub & 0xffff0000u);
}

// ---------------- degree count (deg = 1 + in-degree) ----------------
__global__ void k_deg_count(const int* __restrict__ dst, const int* __restrict__ dstb,
                            int* __restrict__ cntA, int* __restrict__ cntB, int e) {
    int i = blockIdx.x * 256 + threadIdx.x;
    if (i < e) {
        atomicAdd(&cntA[dst[i]], 1);
        atomicAdd(&cntB[dstb[i]], 1);
    }
}

__global__ void k_deg_fin(const int* __restrict__ cntA, const int* __restrict__ cntB,
                          float* __restrict__ dinv, float* __restrict__ deginv,
                          float* __restrict__ dinvb, float* __restrict__ deginvb, int n) {
    int i = blockIdx.x * 256 + threadIdx.x;
    if (i < n) {
        float d = (float)(cntA[i] + 1);
        dinv[i]  = rsqrtf(d);  deginv[i]  = 1.0f / d;
        float db = (float)(cntB[i] + 1);
        dinvb[i] = rsqrtf(db); deginvb[i] = 1.0f / db;
    }
}

// ---------------- 3-phase parallel scan over both edge sets ----------------
__global__ __launch_bounds__(1024) void k_scan1(const int* __restrict__ cntA,
                                                const int* __restrict__ cntB,
                                                int* __restrict__ offA,
                                                int* __restrict__ offB,
                                                int* __restrict__ part) {
    __shared__ int buf[1024];
    int set = blockIdx.x / NCH, chunk = blockIdx.x % NCH;
    const int* cnt = set ? cntB : cntA;
    int* off = set ? offB : offA;
    int tid = threadIdx.x;
    int i = chunk * 1024 + tid;
    int v = (i < NN) ? cnt[i] : 0;
    buf[tid] = v;
    __syncthreads();
    for (int o = 1; o < 1024; o <<= 1) {
        int tv = (tid >= o) ? buf[tid - o] : 0;
        __syncthreads();
        buf[tid] += tv;
        __syncthreads();
    }
    if (i < NN) off[i] = buf[tid] - v;           // chunk-local exclusive
    if (tid == 1023) part[blockIdx.x] = buf[1023];
}

__global__ void k_scan2(int* __restrict__ part, int* __restrict__ offA,
                        int* __restrict__ offB) {
    int tid = threadIdx.x;      // 128 threads = 2 waves
    int lane = tid & 63, s = tid >> 6;
    int v = (lane < NCH) ? part[s * NCH + lane] : 0;
    int orig = v;
    for (int o = 1; o < 64; o <<= 1) {
        int t = __shfl_up(v, o, 64);
        if (lane >= o) v += t;
    }
    if (lane < NCH) part[s * NCH + lane] = v - orig;   // exclusive chunk base
    if (lane == NCH - 1) { if (s) offB[NN] = v; else offA[NN] = v; }
}

__global__ __launch_bounds__(1024) void k_scan3(int* __restrict__ offA,
                                                int* __restrict__ offB,
                                                const int* __restrict__ part) {
    int set = blockIdx.x / NCH, chunk = blockIdx.x % NCH;
    int* off = set ? offB : offA;
    int i = chunk * 1024 + threadIdx.x;
    if (i < NN) off[i] += part[blockIdx.x];
}

// ---------------- CSR fill, both edge sets, perm baked into B ----------------
// record: .x = feature row to gather, .y = dinv[src] bits
__global__ void k_fill2(const int* __restrict__ src, const int* __restrict__ dst,
                        const int* __restrict__ srcb, const int* __restrict__ dstb,
                        const float* __restrict__ dinvA, const float* __restrict__ dinvB,
                        const int* __restrict__ perm,
                        const int* __restrict__ offA, const int* __restrict__ offB,
                        int* __restrict__ curA, int* __restrict__ curB,
                        int2* __restrict__ csrA, int2* __restrict__ csrB) {
    int i = blockIdx.x * 256 + threadIdx.x;
    if (i < NE) {
        int d = dst[i], s = src[i];
        int p = atomicAdd(&curA[d], 1);
        int2 rec; rec.x = s; rec.y = __float_as_int(dinvA[s]);
        csrA[offA[d] + p] = rec;
    } else if (i < 2 * NE) {
        i -= NE;
        int d = dstb[i], s = srcb[i];
        int p = atomicAdd(&curB[d], 1);
        int2 rec; rec.x = perm[s]; rec.y = __float_as_int(dinvB[s]);
        csrB[offB[d] + p] = rec;
    }
}

// ---------------- W -> bf16 transposed [col][k] ----------------
__global__ void k_prepw(const float* __restrict__ W0, const float* __restrict__ W1,
                        const float* __restrict__ W2, unsigned short* __restrict__ Wt) {
    int t = blockIdx.x * 256 + threadIdx.x;
    if (t < 3 * 16384) {
        int m = t >> 14, r = t & 16383;
        int k = r >> 7, c = r & 127;
        const float* W = (m == 0) ? W0 : (m == 1) ? W1 : W2;
        Wt[m * 16384 + c * 128 + k] = f2b(W[r]);
    }
}

// ---------------- x -> bf16: xb = x, xmixb = lam*x + (1-lam)*x[perm] ----------------
__global__ void k_xinit(const float4* __restrict__ x4, const int* __restrict__ perm,
                        const float* __restrict__ lamp,
                        uint2* __restrict__ xb, uint2* __restrict__ xmixb) {
    int t = blockIdx.x * 256 + threadIdx.x;
    if (t < NN * 32) {
        int i = t >> 5, c = t & 31;
        float lam = lamp[0], ml = 1.0f - lam;
        float4 a = x4[t];
        float4 b = x4[(size_t)perm[i] * 32 + c];
        uint2 o1; o1.x = packrtne(a.x, a.y); o1.y = packrtne(a.z, a.w);
        xb[t] = o1;
        uint2 o2;
        o2.x = packrtne(fmaf(lam, a.x, ml * b.x), fmaf(lam, a.y, ml * b.y));
        o2.y = packrtne(fmaf(lam, a.z, ml * b.z), fmaf(lam, a.w, ml * b.w));
        xmixb[t] = o2;
    }
}

// ---------------- fused gather + MFMA layer ----------------
// Block = 32 nodes, 4 waves. Gather: 64 lanes/node (lane owns 2 bf16 features),
// each wave walks 8 nodes sequentially (CLT-balanced trip count, no intra-wave
// divergence). Then 3 MFMA passes sharing W in LDS.
__global__ __launch_bounds__(256) void k_layer(
    const unsigned short* __restrict__ xf,      // x0 features (gather src + pass3 self)
    unsigned short* __restrict__ xmix,          // in/out
    const float* __restrict__ dinv, const float* __restrict__ deginv,
    const float* __restrict__ dinvb, const float* __restrict__ deginvb,
    const int2* __restrict__ csrA, const int* __restrict__ offA,
    const int2* __restrict__ csrB, const int* __restrict__ offB,
    const unsigned short* __restrict__ Wt, const float* __restrict__ bias,
    const float* __restrict__ lamp, unsigned short* __restrict__ x0_out, int do_x0) {
    __shared__ unsigned short Wl[16384];        // 32 KiB [col][k] swizzled
    __shared__ unsigned short st[4096];         // 8 KiB staged tile (swizzled)
    __shared__ unsigned short Ag[4096];         // 8 KiB raw A (linear)

    int tid = threadIdx.x;
    uint4* Wl16 = (uint4*)Wl;
    uint4* st16 = (uint4*)st;
    unsigned* st32 = (unsigned*)st;
    unsigned* Ag32 = (unsigned*)Ag;
    uint4* Ag16 = (uint4*)Ag;
    const uint4* Wg = (const uint4*)Wt;
#pragma unroll
    for (int i = 0; i < 8; ++i) {
        int idx = tid + i * 256;
        Wl16[idx ^ ((idx >> 4) & 7)] = Wg[idx];
    }
    int row0 = blockIdx.x * 32;
    float lam = lamp[0], ml = 1.0f - lam;
    int w = tid >> 6, lane = tid & 63;
    int rt = w & 1, ch = w >> 1;
    int lr = lane & 15, lk = lane >> 4;
    float bcol[4];
#pragma unroll
    for (int ct = 0; ct < 4; ++ct) bcol[ct] = bias[(ch * 4 + ct) * 16 + lr];

    // gather one set: wave w handles nodes w*8..w*8+7; lane owns bf16 cols
    // 2*lane, 2*lane+1. Writes swizzled st (and optionally linear Ag).
    auto gatherset = [&](const int2* csr, const int* off, const float* dntab,
                         const float* dgtab, bool writeAg) {
        for (int r8 = 0; r8 < 8; ++r8) {
            int gnode = w * 8 + r8;
            int grow = row0 + gnode;
            int slot32 = ((gnode * 16 + (lane >> 2)) ^ (gnode & 7)) * 4 + (lane & 3);
            if (grow >= NN) {
                st32[slot32] = 0u;
                if (writeAg) Ag32[gnode * 64 + lane] = 0u;
                continue;
            }
            int t0 = off[grow], t1 = off[grow + 1];
            float a0 = 0.f, a1 = 0.f;
            int t = t0;
            for (; t + 1 < t1; t += 2) {
                int2 r0 = csr[t], r1 = csr[t + 1];
                unsigned v0 = *(const unsigned*)(xf + (size_t)r0.x * 128 + (lane << 1));
                unsigned v1 = *(const unsigned*)(xf + (size_t)r1.x * 128 + (lane << 1));
                float w0 = __int_as_float(r0.y), w1 = __int_as_float(r1.y);
                a0 = fmaf(w0, blo(v0), a0); a1 = fmaf(w0, bhi(v0), a1);
                a0 = fmaf(w1, blo(v1), a0); a1 = fmaf(w1, bhi(v1), a1);
            }
            if (t < t1) {
                int2 r0 = csr[t];
                unsigned v0 = *(const unsigned*)(xf + (size_t)r0.x * 128 + (lane << 1));
                float w0 = __int_as_float(r0.y);
                a0 = fmaf(w0, blo(v0), a0); a1 = fmaf(w0, bhi(v0), a1);
            }
            float dn = dntab[grow], dgv = dgtab[grow];
            a0 *= dn; a1 *= dn;
            unsigned mv = *(const unsigned*)(xmix + (size_t)grow * 128 + (lane << 1));
            st32[slot32] = packrtne(fmaf(blo(mv), dgv, a0), fmaf(bhi(mv), dgv, a1));
            if (writeAg) Ag32[gnode * 64 + lane] = packrtne(a0, a1);
        }
    };

    auto mmpass = [&](f32x4* acc) {
#pragma unroll
        for (int ct = 0; ct < 4; ++ct) {
            float bv = bcol[ct];
            acc[ct] = (f32x4){bv, bv, bv, bv};
        }
#pragma unroll
        for (int kt = 0; kt < 4; ++kt) {
            int k8 = kt * 4 + lk;
            int ar = rt * 16 + lr;
            short8 af = *(const short8*)&st[((ar * 16 + k8) ^ (ar & 7)) * 8];
#pragma unroll
            for (int ct = 0; ct < 4; ++ct) {
                int bc = (ch * 4 + ct) * 16 + lr;
                short8 bf = *(const short8*)&Wl[((bc * 16 + k8) ^ (bc & 7)) * 8];
                acc[ct] = __builtin_amdgcn_mfma_f32_16x16x32_bf16(af, bf, acc[ct], 0, 0, 0);
            }
        }
    };

    f32x4 h[4], g[4];
    // ---- pass 1: h = (A + xmix*dg) W + b ----
    gatherset(csrA, offA, dinv, deginv, true);
    __syncthreads();
    mmpass(h);
    __syncthreads();
    // ---- pass 2: g = (B + xmix*dgb) W + b ; xmix' = lam*relu(h)+(1-lam)*relu(g) ----
    gatherset(csrB, offB, dinvb, deginvb, false);
    __syncthreads();
    mmpass(g);
#pragma unroll
    for (int ct = 0; ct < 4; ++ct) {
        int col = (ch * 4 + ct) * 16 + lr;
#pragma unroll
        for (int j = 0; j < 4; ++j) {
            int gr = row0 + rt * 16 + lk * 4 + j;
            if (gr < NN) {
                float hv = fmaxf(h[ct][j], 0.f), gv = fmaxf(g[ct][j], 0.f);
                xmix[(size_t)gr * 128 + col] = f2b(fmaf(lam, hv, ml * gv));
            }
        }
    }
    // ---- pass 3: x0' = relu((A + x0*dg) W + b) ----
    if (do_x0) {
        __syncthreads();
#pragma unroll
        for (int i2 = 0; i2 < 2; ++i2) {
            int idx = tid + i2 * 256;
            int r = idx >> 4, k8 = idx & 15;
            int gr = row0 + r;
            uint4 o = {0u, 0u, 0u, 0u};
            if (gr < NN) {
                uint4 av = Ag16[idx];
                uint4 xv = *(const uint4*)(xf + (size_t)gr * 128 + k8 * 8);
                float d = deginv[gr];
                o.x = packrtne(fmaf(blo(xv.x), d, blo(av.x)), fmaf(bhi(xv.x), d, bhi(av.x)));
                o.y = packrtne(fmaf(blo(xv.y), d, blo(av.y)), fmaf(bhi(xv.y), d, bhi(av.y)));
                o.z = packrtne(fmaf(blo(xv.z), d, blo(av.z)), fmaf(bhi(xv.z), d, bhi(av.z)));
                o.w = packrtne(fmaf(blo(xv.w), d, blo(av.w)), fmaf(bhi(xv.w), d, bhi(av.w)));
            }
            st16[idx ^ (r & 7)] = o;
        }
        __syncthreads();
        mmpass(g);
#pragma unroll
        for (int ct = 0; ct < 4; ++ct) {
            int col = (ch * 4 + ct) * 16 + lr;
#pragma unroll
            for (int j = 0; j < 4; ++j) {
                int gr = row0 + rt * 16 + lk * 4 + j;
                if (gr < NN)
                    x0_out[(size_t)gr * 128 + col] = f2b(fmaxf(g[ct][j], 0.f));
            }
        }
    }
}

// ---------------- final linear [128->64] + log_softmax (bf16 in, f32 out) ----------------
__global__ __launch_bounds__(256) void k_lin_lsm(
    const unsigned short* __restrict__ X, const float* __restrict__ Wlin,
    const float* __restrict__ blin, float* __restrict__ out) {
    __shared__ __align__(16) float Wl[128 * 64];
    __shared__ float rb[4][128];
    int tid = threadIdx.x;
#pragma unroll
    for (int i = 0; i < 8; ++i)
        ((float4*)Wl)[tid + i * 256] = ((const float4*)Wlin)[tid + i * 256];
    __syncthreads();
    int lane = tid & 63, w = tid >> 6;
    for (int i = blockIdx.x * 4 + w; i < NN; i += gridDim.x * 4) {
        unsigned u = *(const unsigned*)(X + (size_t)i * 128 + lane * 2);
        rb[w][lane * 2]     = blo(u);
        rb[w][lane * 2 + 1] = bhi(u);
        float acc = blin[lane];
#pragma unroll
        for (int k = 0; k < 128; ++k)
            acc = fmaf(rb[w][k], Wl[k * 64 + lane], acc);
        float m = acc;
#pragma unroll
        for (int off = 32; off >= 1; off >>= 1)
            m = fmaxf(m, __shfl_xor(m, off, 64));
        float p = expf(acc - m);
        float s = p;
#pragma unroll
        for (int off = 32; off >= 1; off >>= 1)
            s += __shfl_xor(s, off, 64);
        out[(size_t)i * 64 + lane] = acc - m - logf(s);
    }
}

extern "C" void kernel_launch(void* const* d_in, const int* in_sizes, int n_in,
                              void* d_out, int out_size, void* d_ws, size_t ws_size,
                              hipStream_t stream) {
    const float* x    = (const float*)d_in[0];
    const int*   ei   = (const int*)  d_in[1];
    const int*   eib  = (const int*)  d_in[2];
    const float* lam  = (const float*)d_in[3];
    const int*   perm = (const int*)  d_in[4];
    const float* W0   = (const float*)d_in[5];
    const float* b0   = (const float*)d_in[6];
    const float* W1   = (const float*)d_in[7];
    const float* b1   = (const float*)d_in[8];
    const float* W2   = (const float*)d_in[9];
    const float* b2   = (const float*)d_in[10];
    const float* Wlin = (const float*)d_in[11];
    const float* blin = (const float*)d_in[12];
    float* out = (float*)d_out;

    const int* src  = ei;   const int* dst  = ei + NE;
    const int* srcb = eib;  const int* dstb = eib + NE;

    // ---- workspace layout ----
    char* ws = (char*)d_ws;
    float* dinv    = (float*)ws;                  // N each
    float* deginv  = dinv + NN;
    float* dinvb   = deginv + NN;
    float* deginvb = dinvb + NN;
    int* cntA = (int*)(deginvb + NN);             // contiguous memset block:
    int* cntB = cntA + NN;                        // cntA,cntB,curA,curB (N each)
    int* curA = cntB + NN;
    int* curB = curA + NN;
    int* offA = curB + NN;                        // N+1 (+pad)
    int* offB = offA + (NN + 4);
    int* part = offB + (NN + 4);                  // 98 (+pad)
    char* p = (char*)(part + 128);
    p = (char*)(((size_t)p + 255) & ~(size_t)255);
    int2* csrA = (int2*)p;                        // E records (8B)
    int2* csrB = csrA + NE;
    p = (char*)(csrB + NE);
    p = (char*)(((size_t)p + 255) & ~(size_t)255);
    unsigned short* Wt    = (unsigned short*)p;   // 3 * 16384 bf16
    unsigned short* xb    = Wt + 3 * 16384;       // N*128 bf16 each
    unsigned short* xmixb = xb + (size_t)NN * 128;
    unsigned short* X1    = xmixb + (size_t)NN * 128;
    unsigned short* X2    = X1 + (size_t)NN * 128;

    int gN = (NN + 255) / 256;
    int gE = (NE + 255) / 256;

    // ---- degree norms + CSR build (once; reused by all 3 layers) ----
    hipMemsetAsync(cntA, 0, 4u * NN * sizeof(int), stream);
    k_deg_count<<<gE, 256, 0, stream>>>(dst, dstb, cntA, cntB, NE);
    k_deg_fin<<<gN, 256, 0, stream>>>(cntA, cntB, dinv, deginv, dinvb, deginvb, NN);
    k_scan1<<<2 * NCH, 1024, 0, stream>>>(cntA, cntB, offA, offB, part);
    k_scan2<<<1, 128, 0, stream>>>(part, offA, offB);
    k_scan3<<<2 * NCH, 1024, 0, stream>>>(offA, offB, part);
    k_fill2<<<(2 * NE + 255) / 256, 256, 0, stream>>>(src, dst, srcb, dstb, dinv, dinvb,
                                                      perm, offA, offB, curA, curB,
                                                      csrA, csrB);
    k_prepw<<<192, 256, 0, stream>>>(W0, W1, W2, Wt);
    k_xinit<<<(NN * 32) / 256, 256, 0, stream>>>((const float4*)x, perm, lam,
                                                 (uint2*)xb, (uint2*)xmixb);

    // ---- 3 fused layers ----
    k_layer<<<NBK, 256, 0, stream>>>(xb, xmixb, dinv, deginv, dinvb, deginvb,
                                     csrA, offA, csrB, offB, Wt, b0, lam, X1, 1);
    k_layer<<<NBK, 256, 0, stream>>>(X1, xmixb, dinv, deginv, dinvb, deginvb,
                                     csrA, offA, csrB, offB, Wt + 16384, b1, lam, X2, 1);
    k_layer<<<NBK, 256, 0, stream>>>(X2, xmixb, dinv, deginv, dinvb, deginvb,
                                     csrA, offA, csrB, offB, Wt + 32768, b2, lam,
                                     (unsigned short*)nullptr, 0);

    // ---- logits + log_softmax ----
    k_lin_lsm<<<12500, 256, 0, stream>>>(xmixb, Wlin, blin, out);
}

// Round 8
// 560.440 us; speedup vs baseline: 2.0447x; 2.0447x over previous
//
#include <hip/hip_runtime.h>

#define NN 50000
#define NE 800000
#define NBK 1563          // ceil(NN/32) blocks of 32 nodes
#define NCH 49            // ceil(NN/1024) scan chunks

typedef __attribute__((ext_vector_type(8))) short short8;
typedef __attribute__((ext_vector_type(4))) float f32x4;

// ---- bf16 helpers (RTNE) ----
__device__ inline float blo(unsigned u) { return __uint_as_float(u << 16); }
__device__ inline float bhi(unsigned u) { return __uint_as_float(u & 0xffff0000u); }
__device__ inline unsigned short f2b(float f) {
    unsigned u = __float_as_uint(f);
    u += 0x7fff + ((u >> 16) & 1);
    return (unsigned short)(u >> 16);
}
__device__ inline unsigned packrtne(float a, float b) {
    unsigned ua = __float_as_uint(a); ua += 0x7fff + ((ua >> 16) & 1);
    unsigned ub = __float_as_uint(b); ub += 0x7fff + ((ub >> 16) & 1);
    return (ua >> 16) | (ub & 0xffff0000u);
}
__device__ inline uint4 pack8(const float* f) {
    uint4 o;
    o.x = packrtne(f[0], f[1]); o.y = packrtne(f[2], f[3]);
    o.z = packrtne(f[4], f[5]); o.w = packrtne(f[6], f[7]);
    return o;
}

// ---------------- degree count (deg = 1 + in-degree) ----------------
__global__ void k_deg_count(const int* __restrict__ dst, const int* __restrict__ dstb,
                            int* __restrict__ cntA, int* __restrict__ cntB, int e) {
    int i = blockIdx.x * 256 + threadIdx.x;
    if (i < e) {
        atomicAdd(&cntA[dst[i]], 1);
        atomicAdd(&cntB[dstb[i]], 1);
    }
}

// ---------------- 3-phase parallel scan over both edge sets ----------------
__global__ __launch_bounds__(1024) void k_scan1(const int* __restrict__ cntA,
                                                const int* __restrict__ cntB,
                                                int* __restrict__ offA,
                                                int* __restrict__ offB,
                                                int* __restrict__ part) {
    __shared__ int buf[1024];
    int set = blockIdx.x / NCH, chunk = blockIdx.x % NCH;
    const int* cnt = set ? cntB : cntA;
    int* off = set ? offB : offA;
    int tid = threadIdx.x;
    int i = chunk * 1024 + tid;
    int v = (i < NN) ? cnt[i] : 0;
    buf[tid] = v;
    __syncthreads();
    for (int o = 1; o < 1024; o <<= 1) {
        int tv = (tid >= o) ? buf[tid - o] : 0;
        __syncthreads();
        buf[tid] += tv;
        __syncthreads();
    }
    if (i < NN) off[i] = buf[tid] - v;           // chunk-local exclusive
    if (tid == 1023) part[blockIdx.x] = buf[1023];
}

__global__ void k_scan2(int* __restrict__ part, int* __restrict__ offA,
                        int* __restrict__ offB) {
    int tid = threadIdx.x;      // 128 threads = 2 waves
    int lane = tid & 63, s = tid >> 6;
    int v = (lane < NCH) ? part[s * NCH + lane] : 0;
    int orig = v;
    for (int o = 1; o < 64; o <<= 1) {
        int t = __shfl_up(v, o, 64);
        if (lane >= o) v += t;
    }
    if (lane < NCH) part[s * NCH + lane] = v - orig;   // exclusive chunk base
    if (lane == NCH - 1) { if (s) offB[NN] = v; else offA[NN] = v; }
}

__global__ __launch_bounds__(1024) void k_scan3(int* __restrict__ offA,
                                                int* __restrict__ offB,
                                                const int* __restrict__ part) {
    int set = blockIdx.x / NCH, chunk = blockIdx.x % NCH;
    int* off = set ? offB : offA;
    int i = chunk * 1024 + threadIdx.x;
    if (i < NN) off[i] += part[blockIdx.x];
}

// ---------------- CSR fill, 4-byte records (src only; perm baked into B) ----------------
__global__ void k_fill2(const int* __restrict__ src, const int* __restrict__ dst,
                        const int* __restrict__ srcb, const int* __restrict__ dstb,
                        const int* __restrict__ perm,
                        const int* __restrict__ offA, const int* __restrict__ offB,
                        int* __restrict__ curA, int* __restrict__ curB,
                        int* __restrict__ csrA, int* __restrict__ csrB) {
    int i = blockIdx.x * 256 + threadIdx.x;
    if (i < NE) {
        int d = dst[i];
        int p = atomicAdd(&curA[d], 1);
        csrA[offA[d] + p] = src[i];
    } else if (i < 2 * NE) {
        i -= NE;
        int d = dstb[i];
        int p = atomicAdd(&curB[d], 1);
        csrB[offB[d] + p] = perm[srcb[i]];
    }
}

// ---------------- combined prep: deg tables + W->bf16^T + x->bf16/mix ----------------
__global__ void k_prep(const int* __restrict__ cntA, const int* __restrict__ cntB,
                       const int* __restrict__ perm,
                       float* __restrict__ dinv, float* __restrict__ deginv,
                       float* __restrict__ dinvb, float* __restrict__ dinvbp,
                       float* __restrict__ deginvb,
                       const float* __restrict__ W0, const float* __restrict__ W1,
                       const float* __restrict__ W2, unsigned short* __restrict__ Wt,
                       const float4* __restrict__ x4, const float* __restrict__ lamp,
                       uint2* __restrict__ xb, uint2* __restrict__ xmixb) {
    int b = blockIdx.x;
    if (b < 196) {                       // degree tables
        int i = b * 256 + threadIdx.x;
        if (i < NN) {
            float d = (float)(cntA[i] + 1);
            dinv[i]  = rsqrtf(d);  deginv[i]  = 1.0f / d;
            float db = (float)(cntB[i] + 1);
            float r = rsqrtf(db);
            dinvb[i] = r; deginvb[i] = 1.0f / db;
            dinvbp[perm[i]] = r;         // weight lookup by perm-baked record src
        }
    } else if (b < 388) {                // W -> bf16 transposed [col][k]
        int t = (b - 196) * 256 + threadIdx.x;
        int m = t >> 14, r = t & 16383;
        int k = r >> 7, c = r & 127;
        const float* W = (m == 0) ? W0 : (m == 1) ? W1 : W2;
        Wt[m * 16384 + c * 128 + k] = f2b(W[r]);
    } else {                             // xb = bf16(x); xmixb = bf16(lam*x+(1-lam)*x[perm])
        int t = (b - 388) * 256 + threadIdx.x;
        if (t < NN * 32) {
            int i = t >> 5, c = t & 31;
            float lam = lamp[0], ml = 1.0f - lam;
            float4 a = x4[t];
            float4 bb = x4[(size_t)perm[i] * 32 + c];
            uint2 o1; o1.x = packrtne(a.x, a.y); o1.y = packrtne(a.z, a.w);
            xb[t] = o1;
            uint2 o2;
            o2.x = packrtne(fmaf(lam, a.x, ml * bb.x), fmaf(lam, a.y, ml * bb.y));
            o2.y = packrtne(fmaf(lam, a.z, ml * bb.z), fmaf(lam, a.w, ml * bb.w));
            xmixb[t] = o2;
        }
    }
}

#define ACC8F(a, base, v, wg)                                      \
    a[base+0] = fmaf(wg, blo(v.x), a[base+0]);                     \
    a[base+1] = fmaf(wg, bhi(v.x), a[base+1]);                     \
    a[base+2] = fmaf(wg, blo(v.y), a[base+2]);                     \
    a[base+3] = fmaf(wg, bhi(v.y), a[base+3]);                     \
    a[base+4] = fmaf(wg, blo(v.z), a[base+4]);                     \
    a[base+5] = fmaf(wg, bhi(v.z), a[base+5]);                     \
    a[base+6] = fmaf(wg, blo(v.w), a[base+6]);                     \
    a[base+7] = fmaf(wg, bhi(v.w), a[base+7]);

// ---------------- fused gather + MFMA layer ----------------
// Block = 32 nodes, 4 waves. Gather: 8 lanes/node (lane owns 16B chunks li, li+8),
// 8 concurrent node streams per wave, unroll-2 (4 feature loads in flight).
// Raw A kept in registers for pass 3 (no Ag LDS) -> 40 KB LDS -> 4 blocks/CU.
__global__ __launch_bounds__(256) void k_layer(
    const unsigned short* __restrict__ xf,      // x0 features (gather src + pass3 self)
    unsigned short* __restrict__ xmix,          // in/out
    const float* __restrict__ dinv, const float* __restrict__ deginv,
    const float* __restrict__ dinvb, const float* __restrict__ dinvbp,
    const float* __restrict__ deginvb,
    const int* __restrict__ csrA, const int* __restrict__ offA,
    const int* __restrict__ csrB, const int* __restrict__ offB,
    const unsigned short* __restrict__ Wt, const float* __restrict__ bias,
    const float* __restrict__ lamp, unsigned short* __restrict__ x0_out, int do_x0) {
    __shared__ unsigned short Wl[16384];        // 32 KiB [col][k] swizzled
    __shared__ unsigned short st[4096];         // 8 KiB staged tile (swizzled)

    int tid = threadIdx.x;
    uint4* Wl16 = (uint4*)Wl;
    uint4* st16 = (uint4*)st;
    const uint4* Wg = (const uint4*)Wt;
#pragma unroll
    for (int i = 0; i < 8; ++i) {
        int idx = tid + i * 256;
        Wl16[idx ^ ((idx >> 4) & 7)] = Wg[idx];
    }
    int row0 = blockIdx.x * 32;
    float lam = lamp[0], ml = 1.0f - lam;
    int w = tid >> 6, lane = tid & 63;
    int rt = w & 1, ch = w >> 1;
    int lr = lane & 15, lk = lane >> 4;
    int gnode = w * 8 + (lane >> 3);     // local node 0..31 (8 concurrent per wave)
    int li = lane & 7;                   // owns 16B chunks li and li+8 of the row
    int grow = row0 + gnode;
    int slotL = (gnode * 16 + li) ^ (gnode & 7);
    int slotH = (gnode * 16 + li + 8) ^ (gnode & 7);
    float bcol[4];
#pragma unroll
    for (int ct = 0; ct < 4; ++ct) bcol[ct] = bias[(ch * 4 + ct) * 16 + lr];

    uint4 au0, au1;                      // raw A (scaled, bf16-packed) for pass 3

    // gather one edge set into st (swizzled); optionally keep raw A in regs
    auto gatherset = [&](const int* __restrict__ csr, const int* __restrict__ off,
                         const float* __restrict__ wtab, const float* __restrict__ dntab,
                         const float* __restrict__ dgtab, bool keep) {
        uint4 z = {0u, 0u, 0u, 0u};
        if (grow >= NN) {
            st16[slotL] = z; st16[slotH] = z;
            if (keep) { au0 = z; au1 = z; }
            return;
        }
        float a[16];
#pragma unroll
        for (int k = 0; k < 16; ++k) a[k] = 0.f;
        int t0 = off[grow], t1 = off[grow + 1];
        int t = t0;
        for (; t + 1 < t1; t += 2) {
            int s0 = csr[t], s1 = csr[t + 1];
            float w0 = wtab[s0], w1 = wtab[s1];
            uint4 u0 = *(const uint4*)(xf + (size_t)s0 * 128 + li * 8);
            uint4 u1 = *(const uint4*)(xf + (size_t)s0 * 128 + (li + 8) * 8);
            uint4 u2 = *(const uint4*)(xf + (size_t)s1 * 128 + li * 8);
            uint4 u3 = *(const uint4*)(xf + (size_t)s1 * 128 + (li + 8) * 8);
            ACC8F(a, 0, u0, w0) ACC8F(a, 8, u1, w0)
            ACC8F(a, 0, u2, w1) ACC8F(a, 8, u3, w1)
        }
        if (t < t1) {
            int s0 = csr[t];
            float w0 = wtab[s0];
            uint4 u0 = *(const uint4*)(xf + (size_t)s0 * 128 + li * 8);
            uint4 u1 = *(const uint4*)(xf + (size_t)s0 * 128 + (li + 8) * 8);
            ACC8F(a, 0, u0, w0) ACC8F(a, 8, u1, w0)
        }
        float dn = dntab[grow], dgv = dgtab[grow];
#pragma unroll
        for (int k = 0; k < 16; ++k) a[k] *= dn;
        uint4 m0 = *(const uint4*)(xmix + (size_t)grow * 128 + li * 8);
        uint4 m1 = *(const uint4*)(xmix + (size_t)grow * 128 + (li + 8) * 8);
        float sv[16];
        sv[0]  = fmaf(blo(m0.x), dgv, a[0]);  sv[1]  = fmaf(bhi(m0.x), dgv, a[1]);
        sv[2]  = fmaf(blo(m0.y), dgv, a[2]);  sv[3]  = fmaf(bhi(m0.y), dgv, a[3]);
        sv[4]  = fmaf(blo(m0.z), dgv, a[4]);  sv[5]  = fmaf(bhi(m0.z), dgv, a[5]);
        sv[6]  = fmaf(blo(m0.w), dgv, a[6]);  sv[7]  = fmaf(bhi(m0.w), dgv, a[7]);
        sv[8]  = fmaf(blo(m1.x), dgv, a[8]);  sv[9]  = fmaf(bhi(m1.x), dgv, a[9]);
        sv[10] = fmaf(blo(m1.y), dgv, a[10]); sv[11] = fmaf(bhi(m1.y), dgv, a[11]);
        sv[12] = fmaf(blo(m1.z), dgv, a[12]); sv[13] = fmaf(bhi(m1.z), dgv, a[13]);
        sv[14] = fmaf(blo(m1.w), dgv, a[14]); sv[15] = fmaf(bhi(m1.w), dgv, a[15]);
        st16[slotL] = pack8(sv);
        st16[slotH] = pack8(sv + 8);
        if (keep) { au0 = pack8(a); au1 = pack8(a + 8); }
    };

    auto mmpass = [&](f32x4* acc) {
#pragma unroll
        for (int ct = 0; ct < 4; ++ct) {
            float bv = bcol[ct];
            acc[ct] = (f32x4){bv, bv, bv, bv};
        }
#pragma unroll
        for (int kt = 0; kt < 4; ++kt) {
            int k8 = kt * 4 + lk;
            int ar = rt * 16 + lr;
            short8 af = *(const short8*)&st[((ar * 16 + k8) ^ (ar & 7)) * 8];
#pragma unroll
            for (int ct = 0; ct < 4; ++ct) {
                int bc = (ch * 4 + ct) * 16 + lr;
                short8 bf = *(const short8*)&Wl[((bc * 16 + k8) ^ (bc & 7)) * 8];
                acc[ct] = __builtin_amdgcn_mfma_f32_16x16x32_bf16(af, bf, acc[ct], 0, 0, 0);
            }
        }
    };

    f32x4 h[4], g[4];
    // ---- pass 1: h = (A + xmix*dg) W + b ----
    gatherset(csrA, offA, dinv, dinv, deginv, true);
    __syncthreads();
    mmpass(h);
    __syncthreads();
    // ---- pass 2: g = (B + xmix*dgb) W + b ; xmix' = lam*relu(h)+(1-lam)*relu(g) ----
    gatherset(csrB, offB, dinvbp, dinvb, deginvb, false);
    __syncthreads();
    mmpass(g);
#pragma unroll
    for (int ct = 0; ct < 4; ++ct) {
        int col = (ch * 4 + ct) * 16 + lr;
#pragma unroll
        for (int j = 0; j < 4; ++j) {
            int gr = row0 + rt * 16 + lk * 4 + j;
            if (gr < NN) {
                float hv = fmaxf(h[ct][j], 0.f), gv = fmaxf(g[ct][j], 0.f);
                xmix[(size_t)gr * 128 + col] = f2b(fmaf(lam, hv, ml * gv));
            }
        }
    }
    // ---- pass 3: x0' = relu((A + x0*dg) W + b); A comes from registers ----
    if (do_x0) {
        __syncthreads();
        {
            uint4 o0 = {0u,0u,0u,0u}, o1 = {0u,0u,0u,0u};
            if (grow < NN) {
                float dgv = deginv[grow];
                uint4 x0 = *(const uint4*)(xf + (size_t)grow * 128 + li * 8);
                uint4 x1 = *(const uint4*)(xf + (size_t)grow * 128 + (li + 8) * 8);
                float s0[8], s1[8];
                s0[0] = fmaf(blo(x0.x), dgv, blo(au0.x)); s0[1] = fmaf(bhi(x0.x), dgv, bhi(au0.x));
                s0[2] = fmaf(blo(x0.y), dgv, blo(au0.y)); s0[3] = fmaf(bhi(x0.y), dgv, bhi(au0.y));
                s0[4] = fmaf(blo(x0.z), dgv, blo(au0.z)); s0[5] = fmaf(bhi(x0.z), dgv, bhi(au0.z));
                s0[6] = fmaf(blo(x0.w), dgv, blo(au0.w)); s0[7] = fmaf(bhi(x0.w), dgv, bhi(au0.w));
                s1[0] = fmaf(blo(x1.x), dgv, blo(au1.x)); s1[1] = fmaf(bhi(x1.x), dgv, bhi(au1.x));
                s1[2] = fmaf(blo(x1.y), dgv, blo(au1.y)); s1[3] = fmaf(bhi(x1.y), dgv, bhi(au1.y));
                s1[4] = fmaf(blo(x1.z), dgv, blo(au1.z)); s1[5] = fmaf(bhi(x1.z), dgv, bhi(au1.z));
                s1[6] = fmaf(blo(x1.w), dgv, blo(au1.w)); s1[7] = fmaf(bhi(x1.w), dgv, bhi(au1.w));
                o0 = pack8(s0); o1 = pack8(s1);
            }
            st16[slotL] = o0;
            st16[slotH] = o1;
        }
        __syncthreads();
        mmpass(g);
#pragma unroll
        for (int ct = 0; ct < 4; ++ct) {
            int col = (ch * 4 + ct) * 16 + lr;
#pragma unroll
            for (int j = 0; j < 4; ++j) {
                int gr = row0 + rt * 16 + lk * 4 + j;
                if (gr < NN)
                    x0_out[(size_t)gr * 128 + col] = f2b(fmaxf(g[ct][j], 0.f));
            }
        }
    }
}

// ---------------- final linear [128->64] + log_softmax (bf16 in, f32 out) ----------------
__global__ __launch_bounds__(256) void k_lin_lsm(
    const unsigned short* __restrict__ X, const float* __restrict__ Wlin,
    const float* __restrict__ blin, float* __restrict__ out) {
    __shared__ __align__(16) float Wl[128 * 64];
    __shared__ float rb[4][128];
    int tid = threadIdx.x;
#pragma unroll
    for (int i = 0; i < 8; ++i)
        ((float4*)Wl)[tid + i * 256] = ((const float4*)Wlin)[tid + i * 256];
    __syncthreads();
    int lane = tid & 63, w = tid >> 6;
    for (int i = blockIdx.x * 4 + w; i < NN; i += gridDim.x * 4) {
        unsigned u = *(const unsigned*)(X + (size_t)i * 128 + lane * 2);
        rb[w][lane * 2]     = blo(u);
        rb[w][lane * 2 + 1] = bhi(u);
        float acc = blin[lane];
#pragma unroll
        for (int k = 0; k < 128; ++k)
            acc = fmaf(rb[w][k], Wl[k * 64 + lane], acc);
        float m = acc;
#pragma unroll
        for (int off = 32; off >= 1; off >>= 1)
            m = fmaxf(m, __shfl_xor(m, off, 64));
        float p = expf(acc - m);
        float s = p;
#pragma unroll
        for (int off = 32; off >= 1; off >>= 1)
            s += __shfl_xor(s, off, 64);
        out[(size_t)i * 64 + lane] = acc - m - logf(s);
    }
}

extern "C" void kernel_launch(void* const* d_in, const int* in_sizes, int n_in,
                              void* d_out, int out_size, void* d_ws, size_t ws_size,
                              hipStream_t stream) {
    const float* x    = (const float*)d_in[0];
    const int*   ei   = (const int*)  d_in[1];
    const int*   eib  = (const int*)  d_in[2];
    const float* lam  = (const float*)d_in[3];
    const int*   perm = (const int*)  d_in[4];
    const float* W0   = (const float*)d_in[5];
    const float* b0   = (const float*)d_in[6];
    const float* W1   = (const float*)d_in[7];
    const float* b1   = (const float*)d_in[8];
    const float* W2   = (const float*)d_in[9];
    const float* b2   = (const float*)d_in[10];
    const float* Wlin = (const float*)d_in[11];
    const float* blin = (const float*)d_in[12];
    float* out = (float*)d_out;

    const int* src  = ei;   const int* dst  = ei + NE;
    const int* srcb = eib;  const int* dstb = eib + NE;

    // ---- workspace layout ----
    char* ws = (char*)d_ws;
    float* dinv    = (float*)ws;                  // N each
    float* deginv  = dinv + NN;
    float* dinvb   = deginv + NN;
    float* dinvbp  = dinvb + NN;
    float* deginvb = dinvbp + NN;
    int* cntA = (int*)(deginvb + NN);             // contiguous memset block:
    int* cntB = cntA + NN;                        // cntA,cntB,curA,curB (N each)
    int* curA = cntB + NN;
    int* curB = curA + NN;
    int* offA = curB + NN;                        // N+1 (+pad)
    int* offB = offA + (NN + 4);
    int* part = offB + (NN + 4);                  // 98 (+pad)
    char* p = (char*)(part + 128);
    p = (char*)(((size_t)p + 255) & ~(size_t)255);
    int* csrA = (int*)p;                          // E records (4 B)
    int* csrB = csrA + NE;
    p = (char*)(csrB + NE);
    p = (char*)(((size_t)p + 255) & ~(size_t)255);
    unsigned short* Wt    = (unsigned short*)p;   // 3 * 16384 bf16
    unsigned short* xb    = Wt + 3 * 16384;       // N*128 bf16 each
    unsigned short* xmixb = xb + (size_t)NN * 128;
    unsigned short* X1    = xmixb + (size_t)NN * 128;
    unsigned short* X2    = X1 + (size_t)NN * 128;

    int gE = (NE + 255) / 256;

    // ---- CSR build (once; reused by all 3 layers) ----
    hipMemsetAsync(cntA, 0, 4u * NN * sizeof(int), stream);
    k_deg_count<<<gE, 256, 0, stream>>>(dst, dstb, cntA, cntB, NE);
    k_scan1<<<2 * NCH, 1024, 0, stream>>>(cntA, cntB, offA, offB, part);
    k_scan2<<<1, 128, 0, stream>>>(part, offA, offB);
    k_scan3<<<2 * NCH, 1024, 0, stream>>>(offA, offB, part);
    k_fill2<<<(2 * NE + 255) / 256, 256, 0, stream>>>(src, dst, srcb, dstb, perm,
                                                      offA, offB, curA, curB,
                                                      csrA, csrB);
    // ---- tables + bf16 weights/inputs (one launch) ----
    k_prep<<<388 + (NN * 32) / 256, 256, 0, stream>>>(cntA, cntB, perm,
                                                      dinv, deginv, dinvb, dinvbp, deginvb,
                                                      W0, W1, W2, Wt,
                                                      (const float4*)x, lam,
                                                      (uint2*)xb, (uint2*)xmixb);

    // ---- 3 fused layers ----
    k_layer<<<NBK, 256, 0, stream>>>(xb, xmixb, dinv, deginv, dinvb, dinvbp, deginvb,
                                     csrA, offA, csrB, offB, Wt, b0, lam, X1, 1);
    k_layer<<<NBK, 256, 0, stream>>>(X1, xmixb, dinv, deginv, dinvb, dinvbp, deginvb,
                                     csrA, offA, csrB, offB, Wt + 16384, b1, lam, X2, 1);
    k_layer<<<NBK, 256, 0, stream>>>(X2, xmixb, dinv, deginv, dinvb, dinvbp, deginvb,
                                     csrA, offA, csrB, offB, Wt + 32768, b2, lam,
                                     (unsigned short*)nullptr, 0);

    // ---- logits + log_softmax ----
    k_lin_lsm<<<12500, 256, 0, stream>>>(xmixb, Wlin, blin, out);
}